// Round 2
// baseline (293.605 us; speedup 1.0000x reference)
//
#include <hip/hip_runtime.h>

// DualModel3 R2: fc head + 4096 decoder MLPs, one bf16-MFMA GEMM kernel.
// Round-1 lesson: 272 blocks = 1 block/CU = 11% occupancy, latency-bound
// (MfmaUtil 5.5%, VALU 7%, HBM 9%). Fix: BM 256->64 (grid x4 = 1088 blocks,
// ~4.25/CU), BK 32->64 (half the barriers). Total staging work is invariant
// in BM, so this is pure latency-hiding gain.
//
//   column space: cols 0..1023   = fc head (fcW rows, guard at 1000)
//                 cols 1024..17407 -> decoder c = o*4+h of W1 [IN, O*H]
//   grid: (16 + 256) col-groups x 4 row-groups = 1088 blocks, 256 thr.
//   BM=64, BN=64, BK=64, mfma_f32_16x16x32_bf16, 4 waves x (1m x 4n).
// Decoder epilogue: bias + leaky-relu + W2-weighted H-reduce via __shfl_xor
// over 4 adjacent lanes (C/D layout col=lane&15, row=quad*4+reg, m89).

typedef __bf16 bf16_t;
typedef __bf16 bf16x8 __attribute__((ext_vector_type(8)));
typedef __bf16 bf16x4 __attribute__((ext_vector_type(4)));
typedef float  f32x4  __attribute__((ext_vector_type(4)));

#define LDSTR 72   // bf16 elems per LDS row = 64 + 8 pad -> 144 B (16B-aligned)

__global__ __launch_bounds__(256, 4)
void fused_dual(const float* __restrict__ x,    // [256,2048]
                const float* __restrict__ fcW,  // [1000,2048]
                const float* __restrict__ fcb,  // [1000]
                const float* __restrict__ W1,   // [4096,2048,4] flat
                const float* __restrict__ b1,   // [4096,4] flat
                const float* __restrict__ W2,   // [4096,4] flat
                const float* __restrict__ b2,   // [4096]
                float* __restrict__ out)        // x1 [256*1000] ++ x2 [256*4096]
{
    __shared__ bf16_t lA[64 * LDSTR];   // 9216 B
    __shared__ bf16_t lB[64 * LDSTR];   // 9216 B

    const int tid = threadIdx.x;
    const int blk = blockIdx.x;
    const int cg  = blk >> 2;          // column group (B-tile): 4 sibling blocks
    const int rg  = blk & 3;           // row group
    const int m0  = rg * 64;
    const bool is_fc = (cg < 16);
    const int c0  = (is_fc ? cg : cg - 16) * 64;

    // ---- staging assignment ----
    // A tile [64 rows x 64 k]: thread -> row = tid>>4 (+16r), float4-col = tid&15
    const int a_row = tid >> 4;
    const int a_c4  = tid & 15;
    // B tile [64 n x 64 k]: thread -> n = tid>>2, k-block = tid&3 (16 k's each)
    const int b_n  = tid >> 2;
    const int b_kb = tid & 3;

    const float* ap = x + (m0 + a_row) * 2048 + a_c4 * 4;
    const float* bp;
    if (is_fc) {
        int row = c0 + b_n; if (row > 999) row = 999;   // clamp; stores guarded
        bp = fcW + row * 2048 + b_kb * 16;
    } else {
        // W1 flat addr(floats) = o*8192 + k*4 + h ; col c = o*4+h
        const int o = (c0 >> 2) + (b_n >> 2);
        bp = W1 + o * 8192 + b_kb * 64 + (b_n & 3);
    }

    float4 aR[4];
    float  bR[16];

    // prologue (kt = 0)
    #pragma unroll
    for (int r = 0; r < 4; ++r) aR[r] = *(const float4*)(ap + r * (16 * 2048));
    if (is_fc) {
        #pragma unroll
        for (int q = 0; q < 4; ++q) {
            float4 t = *(const float4*)(bp + q * 4);
            bR[q*4+0] = t.x; bR[q*4+1] = t.y; bR[q*4+2] = t.z; bR[q*4+3] = t.w;
        }
    } else {
        #pragma unroll
        for (int j = 0; j < 16; ++j) bR[j] = bp[j * 4];  // stride 16B, lines filled over j
    }

    const int wav  = tid >> 6;
    const int lane = tid & 63;
    const int l15  = lane & 15;
    const int quad = lane >> 4;

    f32x4 acc[4];
    #pragma unroll
    for (int nt = 0; nt < 4; ++nt) acc[nt] = (f32x4){0.f, 0.f, 0.f, 0.f};

    char* lAb = (char*)lA;
    char* lBb = (char*)lB;
    const int aW = (a_row) * (LDSTR * 2) + a_c4 * 8;       // +16r rows below
    const int bW = b_n * (LDSTR * 2) + b_kb * 32;

    for (int kt = 0; kt < 32; ++kt) {
        __syncthreads();                    // prior iter's frag reads done
        // ---- cvt + LDS write ----
        #pragma unroll
        for (int r = 0; r < 4; ++r) {
            bf16x4 v;
            v[0] = (bf16_t)aR[r].x; v[1] = (bf16_t)aR[r].y;
            v[2] = (bf16_t)aR[r].z; v[3] = (bf16_t)aR[r].w;
            *(bf16x4*)(lAb + aW + r * (16 * LDSTR * 2)) = v;
        }
        {
            bf16x8 v0, v1;
            #pragma unroll
            for (int j = 0; j < 8; ++j) { v0[j] = (bf16_t)bR[j]; v1[j] = (bf16_t)bR[8 + j]; }
            *(bf16x8*)(lBb + bW)      = v0;
            *(bf16x8*)(lBb + bW + 16) = v1;
        }
        __syncthreads();                    // tile visible
        // ---- prefetch next tile (overlaps MFMA) ----
        if (kt != 31) {
            ap += 64;
            bp += is_fc ? 64 : 256;
            #pragma unroll
            for (int r = 0; r < 4; ++r) aR[r] = *(const float4*)(ap + r * (16 * 2048));
            if (is_fc) {
                #pragma unroll
                for (int q = 0; q < 4; ++q) {
                    float4 t = *(const float4*)(bp + q * 4);
                    bR[q*4+0] = t.x; bR[q*4+1] = t.y; bR[q*4+2] = t.z; bR[q*4+3] = t.w;
                }
            } else {
                #pragma unroll
                for (int j = 0; j < 16; ++j) bR[j] = bp[j * 4];
            }
        }
        // ---- fragments + MFMA ----
        // A[m=lane&15][k=quad*8+j], B[k=quad*8+j][n=lane&15]
        #pragma unroll
        for (int kk = 0; kk < 2; ++kk) {
            bf16x8 af = *(const bf16x8*)(lAb + (wav * 16 + l15) * (LDSTR * 2) + kk * 64 + quad * 16);
            #pragma unroll
            for (int nt = 0; nt < 4; ++nt) {
                bf16x8 bf = *(const bf16x8*)(lBb + (nt * 16 + l15) * (LDSTR * 2) + kk * 64 + quad * 16);
                acc[nt] = __builtin_amdgcn_mfma_f32_16x16x32_bf16(af, bf, acc[nt], 0, 0, 0);
            }
        }
    }

    // ---- epilogue ----
    if (is_fc) {
        #pragma unroll
        for (int nt = 0; nt < 4; ++nt) {
            const int c = c0 + nt * 16 + l15;
            const bool valid = (c < 1000);
            const float bias = fcb[valid ? c : 999];
            #pragma unroll
            for (int r = 0; r < 4; ++r) {
                if (valid) {
                    const int row = m0 + wav * 16 + quad * 4 + r;
                    out[row * 1000 + c] = acc[nt][r] + bias;
                }
            }
        }
    } else {
        float* x2out = out + 256 * 1000;
        #pragma unroll
        for (int nt = 0; nt < 4; ++nt) {
            const int c   = c0 + nt * 16 + l15;   // in [0,16384)
            const float b1v = b1[c];
            const float w2v = W2[c];
            const int o   = c >> 2;
            const float b2v = b2[o];
            #pragma unroll
            for (int r = 0; r < 4; ++r) {
                float h = acc[nt][r] + b1v;
                h = (h >= 0.f) ? h : 0.1f * h;        // leaky relu
                float wv = h * w2v;
                wv += __shfl_xor(wv, 1, 64);          // sum 4 h-cols of this decoder
                wv += __shfl_xor(wv, 2, 64);
                if ((lane & 3) == 0) {
                    const int row = m0 + wav * 16 + quad * 4 + r;
                    x2out[row * 4096 + o] = wv + b2v;
                }
            }
        }
    }
}

extern "C" void kernel_launch(void* const* d_in, const int* in_sizes, int n_in,
                              void* d_out, int out_size, void* d_ws, size_t ws_size,
                              hipStream_t stream)
{
    (void)in_sizes; (void)n_in; (void)d_ws; (void)ws_size; (void)out_size;
    const float* x   = (const float*)d_in[0];
    const float* fcW = (const float*)d_in[1];
    const float* fcb = (const float*)d_in[2];
    const float* W1  = (const float*)d_in[3];
    const float* b1  = (const float*)d_in[4];
    const float* W2  = (const float*)d_in[5];
    const float* b2  = (const float*)d_in[6];
    fused_dual<<<1088, 256, 0, stream>>>(x, fcW, fcb, W1, b1, W2, b2, (float*)d_out);
}